// Round 3
// baseline (573.297 us; speedup 1.0000x reference)
//
#include <hip/hip_runtime.h>
#include <math.h>

constexpr int N_VN   = 8000;
constexpr int N_CN   = 4000;
constexpr int DV     = 3;
constexpr int DC     = 6;
constexpr int EDGES  = N_VN * DV;   // 24000
constexpr int BATCH  = 1250;
constexpr int NUM_ITER = 5;
constexpr float LLR_MAX = 20.0f;
// 2*atanh(clip) with clip = f32(1-1e-7) = 1 - 2^-23: log((2-2^-23)/2^-23)
constexpr float MSGMAX = 16.635532f;
constexpr float FFLOOR = 2e-12f;    // floor on (1-ex): reproduces ref's |t|>=1e-12
// int16 log-domain quantization (step 6.1e-4 on mw/msg; validated in R1: the
// tanh-product's pole sensitivity is exactly where ex is tiny -> bounded error)
constexpr float QSCALE = 32767.0f / 20.0f;
constexpr float QINV   = 20.0f / 32767.0f;

constexpr int SLOT_STRIDE = 7;      // 6 edge slots + 1 pad short per CN
                                    // (14B lane stride -> <=2-way banks, free)
constexpr int MTPB  = 1024;         // 16 waves; int16 LDS = 56 KB -> 2 blocks/CU
constexpr int VNPT  = (N_VN + MTPB - 1) / MTPB;   // 8 (r==7 partial: tid<832)

__device__ __forceinline__ short quant_mw(float mv, float w) {
    float mw = fminf(fmaxf(mv * w, -LLR_MAX), LLR_MAX);
    return (short)__float2int_rn(mw * QSCALE);
}

// ---------------------------------------------------------------- graph build
// epos[e] = c*7 + slot : u16 index of edge e in the slot-ordered LDS edge buf.
// Slot order from atomics is arbitrary -> irrelevant (CN product commutes).
__global__ __launch_bounds__(256) void build_graph_k(const int* __restrict__ cn_idx,
                                                     int* __restrict__ cnt,
                                                     int* __restrict__ epos) {
    int e = blockIdx.x * 256 + threadIdx.x;
    if (e >= EDGES) return;
    int c = cn_idx[e];
    int slot = atomicAdd(&cnt[c], 1);
    epos[e] = c * SLOT_STRIDE + slot;
}

// ------------------------------------------------------------- the mega kernel
// One block per batch element, whole 5-iteration BP in 56 KB of int16 LDS.
// 2 blocks/CU (launch_bounds caps VGPR at 64). Persistent regs: Lreg[8] only;
// epos/weights re-read per phase (L2-resident, coalesced).
__global__ __launch_bounds__(MTPB, 8) void bp_mega_k(const float* __restrict__ noise,
                                                     const float* __restrict__ weights,
                                                     const int* __restrict__ epos,
                                                     const int* __restrict__ ebno,
                                                     float* __restrict__ llr_out,
                                                     float* __restrict__ chat_out,
                                                     float* __restrict__ c_out,
                                                     float* __restrict__ loss_part) {
    __shared__ short eS[N_CN * SLOT_STRIDE];   // 56000 B
    __shared__ float hs[2];
    __shared__ float red[MTPB / 64];

    const int b   = blockIdx.x;
    const int tid = threadIdx.x;

    if (tid == 0) {
        double sig2 = 2.0 * pow(10.0, (double)ebno[0] * 0.1);  // 4/no
        hs[0] = (float)(sig2 * 0.5);
        hs[1] = (float)sqrt(sig2);
    }
    __syncthreads();
    const float h = hs[0], s = hs[1];

    const float* nrow = noise    + (size_t)b * N_VN;
    float*       lrow = llr_out  + (size_t)b * N_VN;
    float*       crow = chat_out + (size_t)b * N_VN;
    float*       zrow = c_out    + (size_t)b * N_VN;

    // ---- prologue: llr out, c=0 out, L in regs, iter-0 edge init q(L*w)
    float Lreg[VNPT];
    #pragma unroll
    for (int r = 0; r < VNPT; ++r) {
        int v = tid + r * MTPB;
        if (r < VNPT - 1 || v < N_VN) {
            float nv  = nrow[v];
            float llr = fmaf(s, nv, -h);
            lrow[v]   = llr;
            zrow[v]   = 0.0f;
            Lreg[r]   = -llr;                    // L = -llr
            #pragma unroll
            for (int l = 0; l < DV; ++l) {
                int e = v + l * N_VN;            // vn_idx[e] == e % N_VN
                eS[epos[e]] = quant_mw(Lreg[r], weights[e]);
            }
        }
    }

    float lossacc = 0.0f;
    for (int it = 0; it < NUM_ITER; ++it) {
        __syncthreads();                         // edge buf holds q(mw)
        // ---- CN phase: per-edge leave-one-out message, in-place
        #pragma unroll
        for (int k = 0; k < 4; ++k) {
            int c = tid + k * MTPB;
            if (k < 3 || c < N_CN) {
                short* base = eS + c * SLOT_STRIDE;
                short q[DC];
                float f[DC];
                float num = 1.0f, den = 1.0f;
                unsigned sx = 0u;
                #pragma unroll
                for (int j = 0; j < DC; ++j) {
                    q[j] = base[j];
                    float mw = (float)q[j] * QINV;
                    float ex = __expf(-fabsf(mw));
                    float fl = fmaxf(1.0f - ex, FFLOOR);
                    f[j] = fl;
                    num *= fl;
                    den *= (2.0f - fl);          // == 1+ex (floor err <= 2e-12)
                    sx  ^= (unsigned)(int)q[j];  // sign in bit31 (sext)
                }
                float T = __fdividef(num, den);  // |prod t| (may underflow to +0)
                #pragma unroll
                for (int j = 0; j < DC; ++j) {
                    // 2*atanh(p_j), p_j=T/t_j: (1+p)/(1-p) == (f+T*d)/(f-T*d)
                    float g  = T * (2.0f - f[j]);
                    float r2 = __fdividef(f[j] + g, f[j] - g);
                    float ma = fminf(__logf(r2), MSGMAX);   // inf corner -> clamp
                    unsigned sg = (sx ^ (unsigned)(int)q[j]) & 0x80000000u;
                    float msg = __uint_as_float(__float_as_uint(ma) ^ sg);
                    base[j] = (short)__float2int_rn(msg * QSCALE);
                }
            }
        }
        __syncthreads();                         // edge buf holds q(msg_cn)
        // ---- VN phase: xt, loss, next-iteration q(mw) in-place
        const bool wr = (it != NUM_ITER - 1);
        #pragma unroll
        for (int r = 0; r < VNPT; ++r) {
            int v = tid + r * MTPB;
            if (r < VNPT - 1 || v < N_VN) {
                int e0 = v, e1 = v + N_VN, e2 = v + 2 * N_VN;
                int p0 = epos[e0], p1 = epos[e1], p2 = epos[e2];
                float m0 = (float)eS[p0] * QINV;
                float m1 = (float)eS[p1] * QINV;
                float m2 = (float)eS[p2] * QINV;
                float xt = Lreg[r] + m0 + m1 + m2;
                if (wr) {
                    eS[p0] = quant_mw(xt - m0, weights[e0]);
                    eS[p1] = quant_mw(xt - m1, weights[e1]);
                    eS[p2] = quant_mw(xt - m2, weights[e2]);
                } else {
                    crow[v] = -xt;               // c_hat, coalesced
                }
                // softplus(-xt), stable
                lossacc += fmaxf(-xt, 0.0f) + __logf(1.0f + __expf(-fabsf(xt)));
            }
        }
    }

    // ---- block loss reduction -> loss_part[b]
    #pragma unroll
    for (int off = 32; off > 0; off >>= 1)
        lossacc += __shfl_down(lossacc, off, 64);
    int lane = tid & 63, wid = tid >> 6;
    if (lane == 0) red[wid] = lossacc;
    __syncthreads();
    if (tid == 0) {
        float ssum = 0.0f;
        #pragma unroll
        for (int i = 0; i < MTPB / 64; ++i) ssum += red[i];
        loss_part[b] = ssum;
    }
}

// ---------------------------------------------------- final loss over 1250 blocks
__global__ __launch_bounds__(256) void loss_final_k(const float* __restrict__ lp,
                                                    float* __restrict__ out_loss) {
    double s = 0.0;
    for (int i = threadIdx.x; i < BATCH; i += 256) s += (double)lp[i];
    #pragma unroll
    for (int off = 32; off > 0; off >>= 1)
        s += __shfl_down(s, off, 64);
    __shared__ double red[4];
    int lane = threadIdx.x & 63, wid = threadIdx.x >> 6;
    if (lane == 0) red[wid] = s;
    __syncthreads();
    if (threadIdx.x == 0)
        out_loss[0] = (float)((red[0] + red[1] + red[2] + red[3]) /
                              ((double)NUM_ITER * (double)BATCH * (double)N_VN));
}

// ---------------------------------------------------------------------- launch
extern "C" void kernel_launch(void* const* d_in, const int* in_sizes, int n_in,
                              void* d_out, int out_size, void* d_ws, size_t ws_size,
                              hipStream_t stream) {
    const float* noise   = (const float*)d_in[0];   // (1250, 8000)
    const float* weights = (const float*)d_in[1];   // (24000,)
    // d_in[2] = vn_idx (unused: vn_idx[e] == e % 8000 by construction)
    const int* cn_idx    = (const int*)d_in[3];     // (24000,)
    const int* ebno      = (const int*)d_in[4];     // scalar int

    float* out      = (float*)d_out;
    float* out_c    = out;                 // (1250,8000) zeros (written by mega)
    float* out_chat = out + 10000000;      // (1250,8000)
    float* out_llr  = out + 20000000;      // (1250,8000)
    float* out_loss = out + 30000000;      // scalar

    // workspace (tiny): epos, cn_cnt, loss_part
    char* ws = (char*)d_ws;
    int*   epos      = (int*)(ws);                 // 24000*4 = 96,000
    int*   cn_cnt    = (int*)(ws + 96000);         //  4000*4 = 16,000
    float* loss_part = (float*)(ws + 112000);      //  1250*4 =  5,000

    hipMemsetAsync(cn_cnt, 0, N_CN * sizeof(int), stream);
    build_graph_k<<<dim3((EDGES + 255) / 256), dim3(256), 0, stream>>>(cn_idx, cn_cnt, epos);

    bp_mega_k<<<dim3(BATCH), dim3(MTPB), 0, stream>>>(noise, weights, epos, ebno,
                                                      out_llr, out_chat, out_c, loss_part);

    loss_final_k<<<dim3(1), dim3(256), 0, stream>>>(loss_part, out_loss);
}

// Round 4
// 495.588 us; speedup vs baseline: 1.1568x; 1.1568x over previous
//
#include <hip/hip_runtime.h>
#include <math.h>

constexpr int N_VN   = 8000;
constexpr int N_CN   = 4000;
constexpr int DV     = 3;
constexpr int DC     = 6;
constexpr int EDGES  = N_VN * DV;   // 24000
constexpr int BATCH  = 1250;
constexpr int NUM_ITER = 5;
constexpr float LLR_MAX = 20.0f;    // (encoded in QCLIP: 20 * QSCALE = 32767)
// 2*atanh(clip) with clip = f32(1-1e-7) = 1 - 2^-23: log((2-2^-23)/2^-23)
constexpr float MSGMAX = 16.635532f;
constexpr float FFLOOR = 2e-12f;    // floor on (1-ex): reproduces ref's |t|>=1e-12
// int16 log-domain quantization, step 20/32767 = 6.1e-4 (validated R1/R3)
constexpr float QSCALE = 32767.0f / 20.0f;
constexpr float QINV   = 20.0f / 32767.0f;
constexpr float LOG2E  = 1.44269504f;
constexpr float LN2    = 0.69314718f;
constexpr float C2     = QINV * LOG2E;      // decode: ex = exp2(-|q|*C2)
constexpr float C3     = QSCALE * LN2;      // encode: q = log2(r)*C3
constexpr float QMSGMAX = MSGMAX * QSCALE;  // clamp in quant domain
constexpr float QCLIP   = 32767.0f;         // = LLR_MAX*QSCALE

constexpr int MTPB  = 512;                  // 8 waves; 48KB LDS -> 3 blocks/CU = 24 waves
constexpr int VNPT  = (N_VN + MTPB - 1) / MTPB;  // 16
constexpr int VFULL = N_VN / MTPB;               // 15 full rounds
constexpr int VREM  = N_VN - VFULL * MTPB;       // 368 (guard for r==15)

typedef int aint __attribute__((may_alias));

// ---------------------------------------------------------------- graph build
// epos[e] = c*6 + slot : short index of edge e in the slot-ordered LDS edge buf.
// Slot order from atomics is arbitrary -> irrelevant (CN product commutes).
__global__ __launch_bounds__(256) void build_graph_k(const int* __restrict__ cn_idx,
                                                     int* __restrict__ cnt,
                                                     int* __restrict__ epos) {
    int e = blockIdx.x * 256 + threadIdx.x;
    if (e >= EDGES) return;
    int c = cn_idx[e];
    int slot = atomicAdd(&cnt[c], 1);
    epos[e] = c * DC + slot;
}

// ------------------------------- per-VN packed tables: positions + w*QSCALE
__global__ __launch_bounds__(256) void pack_k(const int* __restrict__ epos,
                                              const float* __restrict__ weights,
                                              ushort4* __restrict__ vp4,
                                              float4* __restrict__ wq4) {
    int v = blockIdx.x * 256 + threadIdx.x;
    if (v >= N_VN) return;
    vp4[v] = make_ushort4((unsigned short)epos[v],
                          (unsigned short)epos[v + N_VN],
                          (unsigned short)epos[v + 2 * N_VN], 0);
    wq4[v] = make_float4(weights[v] * QSCALE,
                         weights[v + N_VN] * QSCALE,
                         weights[v + 2 * N_VN] * QSCALE, 0.0f);
}

// ------------------------------------------------------------- the mega kernel
// One block per batch element; whole 5-iteration BP in 48 KB int16 LDS
// (stride 6 shorts = 12 B per CN -> dword-aligned, CN phase is 3x b32 r/w,
//  banks 3c%32 conflict-free).  3 blocks/CU = 24 waves; VGPR budget ~84.
__global__ __launch_bounds__(MTPB, 6) void bp_mega_k(const float* __restrict__ noise,
                                                     const ushort4* __restrict__ vp4,
                                                     const float4* __restrict__ wq4,
                                                     const int* __restrict__ ebno,
                                                     float* __restrict__ llr_out,
                                                     float* __restrict__ chat_out,
                                                     float* __restrict__ c_out,
                                                     float* __restrict__ loss_part) {
    __shared__ short eS[N_CN * DC];        // 48000 B, no pad
    __shared__ float hs[2];
    __shared__ float red[MTPB / 64];

    const int b   = blockIdx.x;
    const int tid = threadIdx.x;

    if (tid == 0) {
        double sig2 = 2.0 * pow(10.0, (double)ebno[0] * 0.1);  // 4/no
        hs[0] = (float)(sig2 * 0.5);
        hs[1] = (float)sqrt(sig2);
    }
    __syncthreads();
    const float h = hs[0], s = hs[1];

    const float* nrow = noise    + (size_t)b * N_VN;
    float*       lrow = llr_out  + (size_t)b * N_VN;
    float*       crow = chat_out + (size_t)b * N_VN;
    float*       zrow = c_out    + (size_t)b * N_VN;

    // ---- prologue: llr out, c=0 out, L in regs, iter-0 edges q=clamp(L*wq,+-32767)
    float Lreg[VNPT];
    #pragma unroll
    for (int r = 0; r < VNPT; ++r) {
        int v = tid + r * MTPB;
        if (r < VFULL || tid < VREM) {
            float nv  = nrow[v];
            float llr = fmaf(s, nv, -h);
            lrow[v]   = llr;
            zrow[v]   = 0.0f;
            float Lv  = -llr;                 // L = -llr
            Lreg[r]   = Lv;
            ushort4 p4 = vp4[v];
            float4  w4 = wq4[v];
            float t0 = fminf(fmaxf(Lv * w4.x, -QCLIP), QCLIP);
            float t1 = fminf(fmaxf(Lv * w4.y, -QCLIP), QCLIP);
            float t2 = fminf(fmaxf(Lv * w4.z, -QCLIP), QCLIP);
            eS[p4.x] = (short)(int)t0;
            eS[p4.y] = (short)(int)t1;
            eS[p4.z] = (short)(int)t2;
        }
    }

    float spMax = 0.0f, spLog = 0.0f;
    #pragma unroll 1
    for (int it = 0; it < NUM_ITER; ++it) {
        __syncthreads();                      // edge buf holds q(mw)
        // ---- CN phase: dword-ized leave-one-out messages, in-place
        #pragma unroll 2
        for (int c = tid; c < N_CN; c += MTPB) {
            aint* bi = (aint*)(eS + c * DC);  // c*12 B, 4B-aligned, exclusive dwords
            int d0 = bi[0], d1 = bi[1], d2 = bi[2];
            int q[DC] = { (int)(short)d0, d0 >> 16,
                          (int)(short)d1, d1 >> 16,
                          (int)(short)d2, d2 >> 16 };
            float f[DC];
            float num = 1.0f, den = 1.0f;
            int sx = 0;
            #pragma unroll
            for (int j = 0; j < DC; ++j) {
                float aq = (float)q[j];
                float ex = exp2f(-fabsf(aq) * C2);      // exp(-|mw|)
                float fl = fmaxf(1.0f - ex, FFLOOR);
                f[j] = fl;
                num *= fl;
                den *= (2.0f - fl);                     // == 1+ex
                sx  ^= q[j];                            // sign parity in bit31
            }
            float T = __fdividef(num, den);             // |prod t| (underflow->+0 ok)
            int od[3];
            #pragma unroll
            for (int jp = 0; jp < 3; ++jp) {
                int qq[2];
                #pragma unroll
                for (int hh = 0; hh < 2; ++hh) {
                    int j = jp * 2 + hh;
                    // 2*atanh(p_j), p_j=T/t_j: (1+p)/(1-p) == (f+T*d)/(f-T*d)
                    float g  = T * (2.0f - f[j]);
                    float rr = __fdividef(f[j] + g, f[j] - g);
                    float ql = fminf(__log2f(rr) * C3, QMSGMAX);  // NaN/inf -> clamp
                    unsigned sg = (unsigned)(sx ^ q[j]) & 0x80000000u;
                    float ms = __uint_as_float(__float_as_uint(ql) ^ sg);
                    qq[hh] = (int)ms;                   // rz, |.|<=32767
                }
                od[jp] = (qq[0] & 0xffff) | (qq[1] << 16);
            }
            bi[0] = od[0]; bi[1] = od[1]; bi[2] = od[2];
        }
        __syncthreads();                      // edge buf holds q(msg_cn)
        // ---- VN phase: xt, loss, next-iteration q(mw) in-place
        const bool wr = (it != NUM_ITER - 1);
        #pragma unroll
        for (int r = 0; r < VNPT; ++r) {
            int v = tid + r * MTPB;
            if (r < VFULL || tid < VREM) {
                ushort4 p4 = vp4[v];
                int q0 = (int)eS[p4.x];
                int q1 = (int)eS[p4.y];
                int q2 = (int)eS[p4.z];
                float xt = fmaf((float)(q0 + q1 + q2), QINV, Lreg[r]);
                if (wr) {
                    float4 w4 = wq4[v];
                    float m0 = fmaf((float)q0, -QINV, xt);   // xt - msg0
                    float m1 = fmaf((float)q1, -QINV, xt);
                    float m2 = fmaf((float)q2, -QINV, xt);
                    float t0 = fminf(fmaxf(m0 * w4.x, -QCLIP), QCLIP);
                    float t1 = fminf(fmaxf(m1 * w4.y, -QCLIP), QCLIP);
                    float t2 = fminf(fmaxf(m2 * w4.z, -QCLIP), QCLIP);
                    eS[p4.x] = (short)(int)t0;
                    eS[p4.y] = (short)(int)t1;
                    eS[p4.z] = (short)(int)t2;
                } else {
                    crow[v] = -xt;            // c_hat, coalesced
                }
                // softplus(-xt) split: max-part + ln2*log2-part (folded once)
                spMax += fmaxf(-xt, 0.0f);
                spLog += __log2f(1.0f + exp2f(-fabsf(xt) * LOG2E));
            }
        }
    }
    float lossacc = fmaf(LN2, spLog, spMax);

    // ---- block loss reduction -> loss_part[b]
    #pragma unroll
    for (int off = 32; off > 0; off >>= 1)
        lossacc += __shfl_down(lossacc, off, 64);
    int lane = tid & 63, wid = tid >> 6;
    if (lane == 0) red[wid] = lossacc;
    __syncthreads();
    if (tid == 0) {
        float ssum = 0.0f;
        #pragma unroll
        for (int i = 0; i < MTPB / 64; ++i) ssum += red[i];
        loss_part[b] = ssum;
    }
}

// ---------------------------------------------------- final loss over 1250 blocks
__global__ __launch_bounds__(256) void loss_final_k(const float* __restrict__ lp,
                                                    float* __restrict__ out_loss) {
    double s = 0.0;
    for (int i = threadIdx.x; i < BATCH; i += 256) s += (double)lp[i];
    #pragma unroll
    for (int off = 32; off > 0; off >>= 1)
        s += __shfl_down(s, off, 64);
    __shared__ double red[4];
    int lane = threadIdx.x & 63, wid = threadIdx.x >> 6;
    if (lane == 0) red[wid] = s;
    __syncthreads();
    if (threadIdx.x == 0)
        out_loss[0] = (float)((red[0] + red[1] + red[2] + red[3]) /
                              ((double)NUM_ITER * (double)BATCH * (double)N_VN));
}

// ---------------------------------------------------------------------- launch
extern "C" void kernel_launch(void* const* d_in, const int* in_sizes, int n_in,
                              void* d_out, int out_size, void* d_ws, size_t ws_size,
                              hipStream_t stream) {
    const float* noise   = (const float*)d_in[0];   // (1250, 8000)
    const float* weights = (const float*)d_in[1];   // (24000,)
    // d_in[2] = vn_idx (unused: vn_idx[e] == e % 8000 by construction)
    const int* cn_idx    = (const int*)d_in[3];     // (24000,)
    const int* ebno      = (const int*)d_in[4];     // scalar int

    float* out      = (float*)d_out;
    float* out_c    = out;                 // (1250,8000) zeros (written by mega)
    float* out_chat = out + 10000000;      // (1250,8000)
    float* out_llr  = out + 20000000;      // (1250,8000)
    float* out_loss = out + 30000000;      // scalar

    // workspace (~309 KB), all offsets 16B-aligned
    char* ws = (char*)d_ws;
    int*     epos      = (int*)(ws);                // 24000*4 =  96,000
    int*     cn_cnt    = (int*)(ws + 96000);        //  4000*4 =  16,000
    ushort4* vp4       = (ushort4*)(ws + 112000);   //  8000*8 =  64,000
    float4*  wq4       = (float4*)(ws + 176000);    //  8000*16= 128,000
    float*   loss_part = (float*)(ws + 304000);     //  1250*4 =   5,000

    hipMemsetAsync(cn_cnt, 0, N_CN * sizeof(int), stream);
    build_graph_k<<<dim3((EDGES + 255) / 256), dim3(256), 0, stream>>>(cn_idx, cn_cnt, epos);
    pack_k<<<dim3((N_VN + 255) / 256), dim3(256), 0, stream>>>(epos, weights, vp4, wq4);

    bp_mega_k<<<dim3(BATCH), dim3(MTPB), 0, stream>>>(noise, vp4, wq4, ebno,
                                                      out_llr, out_chat, out_c, loss_part);

    loss_final_k<<<dim3(1), dim3(256), 0, stream>>>(loss_part, out_loss);
}

// Round 5
// 409.323 us; speedup vs baseline: 1.4006x; 1.2107x over previous
//
#include <hip/hip_runtime.h>
#include <math.h>

constexpr int N_VN   = 8000;
constexpr int N_CN   = 4000;
constexpr int DV     = 3;
constexpr int DC     = 6;
constexpr int EDGES  = N_VN * DV;   // 24000
constexpr int BATCH  = 1250;
constexpr int NUM_ITER = 5;
// 2*atanh(clip) with clip = f32(1-1e-7) = 1 - 2^-23: log((2-2^-23)/2^-23)
constexpr float MSGMAX = 16.635532f;
constexpr float FFLOOR = 2e-12f;    // floor on (1-ex): reproduces ref's |t|>=1e-12
// int16 log-domain quantization, step 20/32767 = 6.1e-4 (validated R1/R3)
constexpr float QSCALE = 32767.0f / 20.0f;
constexpr float QINV   = 20.0f / 32767.0f;
constexpr float LOG2E  = 1.44269504f;
constexpr float LN2    = 0.69314718f;
constexpr float C2     = QINV * LOG2E;      // decode: ex = exp2(-|q|*C2)
constexpr float C3     = QSCALE * LN2;      // encode: q = log2(r)*C3
constexpr float QMSGMAX = MSGMAX * QSCALE;  // clamp in quant domain
constexpr float QCLIP   = 32767.0f;         // = LLR_MAX*QSCALE

constexpr int MTPB  = 1024;                 // 16 waves; 48KB LDS -> 2 blocks/CU = 32 waves
constexpr int VNPT  = (N_VN + MTPB - 1) / MTPB;  // 8
constexpr int VFULL = N_VN / MTPB;               // 7 full rounds
constexpr int VREM  = N_VN - VFULL * MTPB;       // 832 (guard for r==7)

typedef int aint __attribute__((may_alias));

// ---------------------------------------------------------------- graph build
// epos[e] = c*6 + slot : short index of edge e in the slot-ordered LDS edge buf.
// Slot order from atomics is arbitrary -> irrelevant (CN product commutes).
__global__ __launch_bounds__(256) void build_graph_k(const int* __restrict__ cn_idx,
                                                     int* __restrict__ cnt,
                                                     int* __restrict__ epos) {
    int e = blockIdx.x * 256 + threadIdx.x;
    if (e >= EDGES) return;
    int c = cn_idx[e];
    int slot = atomicAdd(&cnt[c], 1);
    epos[e] = c * DC + slot;
}

// ------------------------------- per-VN packed tables: positions + w*QSCALE
__global__ __launch_bounds__(256) void pack_k(const int* __restrict__ epos,
                                              const float* __restrict__ weights,
                                              ushort4* __restrict__ vp4,
                                              float4* __restrict__ wq4) {
    int v = blockIdx.x * 256 + threadIdx.x;
    if (v >= N_VN) return;
    vp4[v] = make_ushort4((unsigned short)epos[v],
                          (unsigned short)epos[v + N_VN],
                          (unsigned short)epos[v + 2 * N_VN], 0);
    wq4[v] = make_float4(weights[v] * QSCALE,
                         weights[v + N_VN] * QSCALE,
                         weights[v + 2 * N_VN] * QSCALE, 0.0f);
}

// ------------------------------------------------------------- the mega kernel
// One block per batch element; whole 5-iteration BP in 48 KB int16 LDS
// (stride 6 shorts = 12 B per CN -> dword-aligned, CN phase is 3x b32 r/w,
//  banks 3c%32 <=2-way = free).  2 blocks/CU = 32 waves (LDS-capped, no
//  min-waves clause: R3/R4 showed it causes catastrophic spill traffic).
// Steady state touches NO global memory: positions/weights/L all persistent
// in registers (~56 VGPR), edge state in LDS.
__global__ __launch_bounds__(MTPB) void bp_mega_k(const float* __restrict__ noise,
                                                  const ushort4* __restrict__ vp4,
                                                  const float4* __restrict__ wq4,
                                                  const int* __restrict__ ebno,
                                                  float* __restrict__ llr_out,
                                                  float* __restrict__ chat_out,
                                                  float* __restrict__ c_out,
                                                  float* __restrict__ loss_part) {
    __shared__ short eS[N_CN * DC];        // 48000 B, no pad
    __shared__ float hs[2];
    __shared__ float red[MTPB / 64];

    const int b   = blockIdx.x;
    const int tid = threadIdx.x;

    if (tid == 0) {
        double sig2 = 2.0 * pow(10.0, (double)ebno[0] * 0.1);  // 4/no
        hs[0] = (float)(sig2 * 0.5);
        hs[1] = (float)sqrt(sig2);
    }
    __syncthreads();
    const float h = hs[0], s = hs[1];

    const float* nrow = noise    + (size_t)b * N_VN;
    float*       lrow = llr_out  + (size_t)b * N_VN;
    float*       crow = chat_out + (size_t)b * N_VN;
    float*       zrow = c_out    + (size_t)b * N_VN;

    // ---- prologue: llr/c out, persistent tables into regs, iter-0 edge init
    float Lreg[VNPT];
    int   pp[VNPT][DV];
    float wq[VNPT][DV];
    #pragma unroll
    for (int r = 0; r < VNPT; ++r) {
        int v = tid + r * MTPB;
        if (r < VFULL || tid < VREM) {
            float nv  = nrow[v];
            float llr = fmaf(s, nv, -h);
            lrow[v]   = llr;
            zrow[v]   = 0.0f;
            float Lv  = -llr;                 // L = -llr
            Lreg[r]   = Lv;
            ushort4 p4 = vp4[v];
            float4  w4 = wq4[v];
            pp[r][0] = p4.x; pp[r][1] = p4.y; pp[r][2] = p4.z;
            wq[r][0] = w4.x; wq[r][1] = w4.y; wq[r][2] = w4.z;
            #pragma unroll
            for (int l = 0; l < DV; ++l) {
                float t = fminf(fmaxf(Lv * wq[r][l], -QCLIP), QCLIP);
                eS[pp[r][l]] = (short)__float2int_rn(t);
            }
        }
    }

    float spMax = 0.0f, spLog = 0.0f;
    #pragma unroll 1
    for (int it = 0; it < NUM_ITER; ++it) {
        __syncthreads();                      // edge buf holds q(mw)
        // ---- CN phase: dword-ized leave-one-out messages, in-place
        #pragma unroll 1
        for (int c = tid; c < N_CN; c += MTPB) {
            aint* bi = (aint*)(eS + c * DC);  // c*12 B, 4B-aligned, exclusive dwords
            int d0 = bi[0], d1 = bi[1], d2 = bi[2];
            int q[DC] = { (int)(short)d0, d0 >> 16,
                          (int)(short)d1, d1 >> 16,
                          (int)(short)d2, d2 >> 16 };
            float f[DC];
            float num = 1.0f, den = 1.0f;
            int sx = 0;
            #pragma unroll
            for (int j = 0; j < DC; ++j) {
                float aq = (float)q[j];
                float ex = exp2f(-fabsf(aq) * C2);      // exp(-|mw|)
                float fl = fmaxf(1.0f - ex, FFLOOR);
                f[j] = fl;
                num *= fl;
                den *= (2.0f - fl);                     // == 1+ex
                sx  ^= q[j];                            // sign parity in bit31
            }
            float T = __fdividef(num, den);             // |prod t| (underflow->+0 ok)
            int od[3];
            #pragma unroll
            for (int jp = 0; jp < 3; ++jp) {
                int qq[2];
                #pragma unroll
                for (int hh = 0; hh < 2; ++hh) {
                    int j = jp * 2 + hh;
                    // 2*atanh(p_j), p_j=T/t_j: (1+p)/(1-p) == (f+T*d)/(f-T*d)
                    float g  = T * (2.0f - f[j]);
                    float rr = __fdividef(f[j] + g, f[j] - g);
                    float ql = fminf(__log2f(rr) * C3, QMSGMAX);  // NaN/inf -> clamp
                    unsigned sg = (unsigned)(sx ^ q[j]) & 0x80000000u;
                    float ms = __uint_as_float(__float_as_uint(ql) ^ sg);
                    qq[hh] = __float2int_rn(ms);        // rn, |.| <= 27258
                }
                od[jp] = (qq[0] & 0xffff) | (qq[1] << 16);
            }
            bi[0] = od[0]; bi[1] = od[1]; bi[2] = od[2];
        }
        __syncthreads();                      // edge buf holds q(msg_cn)
        // ---- VN phase: xt, loss, next-iteration q(mw) in-place (regs only)
        const bool wr = (it != NUM_ITER - 1);
        #pragma unroll
        for (int r = 0; r < VNPT; ++r) {
            int v = tid + r * MTPB;
            if (r < VFULL || tid < VREM) {
                int q0 = (int)eS[pp[r][0]];
                int q1 = (int)eS[pp[r][1]];
                int q2 = (int)eS[pp[r][2]];
                float xt = fmaf((float)(q0 + q1 + q2), QINV, Lreg[r]);
                if (wr) {
                    float m0 = fmaf((float)q0, -QINV, xt);   // xt - msg0
                    float m1 = fmaf((float)q1, -QINV, xt);
                    float m2 = fmaf((float)q2, -QINV, xt);
                    float t0 = fminf(fmaxf(m0 * wq[r][0], -QCLIP), QCLIP);
                    float t1 = fminf(fmaxf(m1 * wq[r][1], -QCLIP), QCLIP);
                    float t2 = fminf(fmaxf(m2 * wq[r][2], -QCLIP), QCLIP);
                    eS[pp[r][0]] = (short)__float2int_rn(t0);
                    eS[pp[r][1]] = (short)__float2int_rn(t1);
                    eS[pp[r][2]] = (short)__float2int_rn(t2);
                } else {
                    crow[v] = -xt;            // c_hat, coalesced
                }
                // softplus(-xt) split: max-part + ln2*log2-part (folded once)
                spMax += fmaxf(-xt, 0.0f);
                spLog += __log2f(1.0f + exp2f(-fabsf(xt) * LOG2E));
            }
        }
    }
    float lossacc = fmaf(LN2, spLog, spMax);

    // ---- block loss reduction -> loss_part[b]
    #pragma unroll
    for (int off = 32; off > 0; off >>= 1)
        lossacc += __shfl_down(lossacc, off, 64);
    int lane = tid & 63, wid = tid >> 6;
    if (lane == 0) red[wid] = lossacc;
    __syncthreads();
    if (tid == 0) {
        float ssum = 0.0f;
        #pragma unroll
        for (int i = 0; i < MTPB / 64; ++i) ssum += red[i];
        loss_part[b] = ssum;
    }
}

// ---------------------------------------------------- final loss over 1250 blocks
__global__ __launch_bounds__(256) void loss_final_k(const float* __restrict__ lp,
                                                    float* __restrict__ out_loss) {
    double s = 0.0;
    for (int i = threadIdx.x; i < BATCH; i += 256) s += (double)lp[i];
    #pragma unroll
    for (int off = 32; off > 0; off >>= 1)
        s += __shfl_down(s, off, 64);
    __shared__ double red[4];
    int lane = threadIdx.x & 63, wid = threadIdx.x >> 6;
    if (lane == 0) red[wid] = s;
    __syncthreads();
    if (threadIdx.x == 0)
        out_loss[0] = (float)((red[0] + red[1] + red[2] + red[3]) /
                              ((double)NUM_ITER * (double)BATCH * (double)N_VN));
}

// ---------------------------------------------------------------------- launch
extern "C" void kernel_launch(void* const* d_in, const int* in_sizes, int n_in,
                              void* d_out, int out_size, void* d_ws, size_t ws_size,
                              hipStream_t stream) {
    const float* noise   = (const float*)d_in[0];   // (1250, 8000)
    const float* weights = (const float*)d_in[1];   // (24000,)
    // d_in[2] = vn_idx (unused: vn_idx[e] == e % 8000 by construction)
    const int* cn_idx    = (const int*)d_in[3];     // (24000,)
    const int* ebno      = (const int*)d_in[4];     // scalar int

    float* out      = (float*)d_out;
    float* out_c    = out;                 // (1250,8000) zeros (written by mega)
    float* out_chat = out + 10000000;      // (1250,8000)
    float* out_llr  = out + 20000000;      // (1250,8000)
    float* out_loss = out + 30000000;      // scalar

    // workspace (~309 KB), all offsets 16B-aligned
    char* ws = (char*)d_ws;
    int*     epos      = (int*)(ws);                // 24000*4 =  96,000
    int*     cn_cnt    = (int*)(ws + 96000);        //  4000*4 =  16,000
    ushort4* vp4       = (ushort4*)(ws + 112000);   //  8000*8 =  64,000
    float4*  wq4       = (float4*)(ws + 176000);    //  8000*16= 128,000
    float*   loss_part = (float*)(ws + 304000);     //  1250*4 =   5,000

    hipMemsetAsync(cn_cnt, 0, N_CN * sizeof(int), stream);
    build_graph_k<<<dim3((EDGES + 255) / 256), dim3(256), 0, stream>>>(cn_idx, cn_cnt, epos);
    pack_k<<<dim3((N_VN + 255) / 256), dim3(256), 0, stream>>>(epos, weights, vp4, wq4);

    bp_mega_k<<<dim3(BATCH), dim3(MTPB), 0, stream>>>(noise, vp4, wq4, ebno,
                                                      out_llr, out_chat, out_c, loss_part);

    loss_final_k<<<dim3(1), dim3(256), 0, stream>>>(loss_part, out_loss);
}